// Round 3
// baseline (187.415 us; speedup 1.0000x reference)
//
#include <hip/hip_runtime.h>

#define THREADS 512

// raw barrier: wait LDS ops only (NOT vmcnt) so prefetch loads / retire stores
// stay in flight across the barrier. "memory" clobber pins C++ LDS access order.
#define BAR() do { asm volatile("s_waitcnt lgkmcnt(0)" ::: "memory"); \
                   __builtin_amdgcn_s_barrier();                      \
                   asm volatile("" ::: "memory"); } while (0)

// -------- radix-8 inverse DFT over register index: u[n] = sum_k v[k] e^{+2*pi*i*n*k/8}
__device__ __forceinline__ void dft8(float* vr, float* vi) {
    float t0r=vr[0]+vr[4], t0i=vi[0]+vi[4];
    float t1r=vr[0]-vr[4], t1i=vi[0]-vi[4];
    float t2r=vr[2]+vr[6], t2i=vi[2]+vi[6];
    float t3r=vr[2]-vr[6], t3i=vi[2]-vi[6];
    float t4r=vr[1]+vr[5], t4i=vi[1]+vi[5];
    float t5r=vr[1]-vr[5], t5i=vi[1]-vi[5];
    float t6r=vr[3]+vr[7], t6i=vi[3]+vi[7];
    float t7r=vr[3]-vr[7], t7i=vi[3]-vi[7];
    float e0r=t0r+t2r, e0i=t0i+t2i;
    float e1r=t1r-t3i, e1i=t1i+t3r;   // t1 + i*t3
    float e2r=t0r-t2r, e2i=t0i-t2i;
    float e3r=t1r+t3i, e3i=t1i-t3r;   // t1 - i*t3
    float o0r=t4r+t6r, o0i=t4i+t6i;
    float o1r=t5r-t7i, o1i=t5i+t7r;
    float o2r=t4r-t6r, o2i=t4i-t6i;
    float o3r=t5r+t7i, o3i=t5i-t7r;
    const float C = 0.70710678118654752f;
    float w1r = C*(o1r - o1i), w1i = C*(o1r + o1i);   // W8^1 * o1
    float w2r = -o2i,          w2i = o2r;             // i * o2
    float w3r = -C*(o3r + o3i), w3i = C*(o3r - o3i);  // W8^3 * o3
    vr[0]=e0r+o0r; vi[0]=e0i+o0i;
    vr[1]=e1r+w1r; vi[1]=e1i+w1i;
    vr[2]=e2r+w2r; vi[2]=e2i+w2i;
    vr[3]=e3r+w3r; vi[3]=e3i+w3i;
    vr[4]=e0r-o0r; vi[4]=e0i-o0i;
    vr[5]=e1r-w1r; vi[5]=e1i-w1i;
    vr[6]=e2r-w2r; vi[6]=e2i-w2i;
    vr[7]=e3r-w3r; vi[7]=e3i-w3i;
}

// retire one owned sample p (block-local, window [0,8960)) with accumulated value a
__device__ __forceinline__ void retire_one(int p, float a, int gg,
                                           const float* s_wt, const float* s_envr,
                                           const float* s_ps,
                                           float* yout, float* mout, int P0)
{
    if (p < 768) {
        if (gg > 0) { atomicAdd(&yout[P0 + p - 384], a); return; }
        if (p < 384) return;                 // trimmed pad
    } else if (p >= 8192) {
        if (gg < 63) { atomicAdd(&yout[P0 + p - 384], a); return; }
        if (p >= 8576) return;               // trimmed pad
    }
    int thi = p >> 8;                        // block-local last frame
    int tlo = (p >= 768) ? ((p - 768) >> 8) : 0;
    float fm = s_ps[min(32, thi + 1)] - s_ps[tlo];
    float envr;
    if (p >= 768 && p < 8192) {
        envr = s_envr[p & 255];              // periodic interior, reciprocal
    } else {
        float e = 0.f;
        int fhi = min(31, thi);
        for (int t = tlo; t <= fhi; ++t) {
            float w = s_wt[p - (t << 8)] * 512.0f;
            e += w * w;
        }
        envr = 1.0f / e;
    }
    int s = P0 + p - 384;
    yout[s] = a * envr;
    mout[s] = (fm > 0.f) ? 1.0f : 0.0f;
}

// main: one block = (batch b, 32 frames). 512 threads = 8 waves, 4 rounds x 8 frames.
__global__ __launch_bounds__(512, 8) void istft_main(const float* __restrict__ spec_re,
                                                     const float* __restrict__ spec_im,
                                                     const float* __restrict__ mask,
                                                     float* __restrict__ out)
{
    const int gg  = blockIdx.x;   // frame-group 0..63 (frames [32g, 32g+32))
    const int b   = blockIdx.y;   // batch 0..15
    const int tid = threadIdx.x;

    __shared__ float  s_slot[8320];   // 8 slots x 520: re at [slot*520+n], im at +4160
    __shared__ float  s_wt[1024];     // hann(j)/512
    __shared__ float  s_envr[256];    // 1 / (periodic fold of hann^2)
    __shared__ float  s_mask[32];     // mask[b, 32g .. 32g+32)
    __shared__ float  s_ps[33];       // prefix sums of s_mask
    __shared__ float2 s_twzb[64];     // e^{i*pi*l/512}
    __shared__ float2 s_tw64[8];      // e^{2*pi*i*a/64}
    __shared__ float2 s_tw512[64];    // e^{2*pi*i*l/512}

    for (int i = tid; i < 1024; i += THREADS) {
        float w = 0.5f - 0.5f * cosf(6.2831853071795864f * (float)i * (1.0f/1024.0f));
        s_wt[i] = w * (1.0f/512.0f);
    }
    if (tid < 256) {
        float e = 0.f;
        for (int k = 0; k < 4; ++k) {
            float w = 0.5f - 0.5f * cosf(6.2831853071795864f * (float)(tid + (k<<8)) * (1.0f/1024.0f));
            e += w * w;
        }
        s_envr[tid] = 1.0f / e;
    }
    if (tid < 64) {
        float a1 = 3.1415926535897932f * (float)tid * (1.0f/512.0f);
        s_twzb[tid] = make_float2(cosf(a1), sinf(a1));
        float a2 = 6.2831853071795864f * (float)tid * (1.0f/512.0f);
        s_tw512[tid] = make_float2(cosf(a2), sinf(a2));
    }
    if (tid < 8) {
        float a = 6.2831853071795864f * (float)tid * (1.0f/64.0f);
        s_tw64[tid] = make_float2(cosf(a), sinf(a));
    }
    if (tid < 32) s_mask[tid] = mask[b*2048 + gg*32 + tid];
    __syncthreads();                   // publish s_mask (before any prefetch loads issue)
    if (tid == 0) {                    // tiny serial prefix over 32 mask values
        float acc = 0.f;
        s_ps[0] = 0.f;
        for (int i = 0; i < 32; ++i) { acc += s_mask[i]; s_ps[i+1] = acc; }
    }

    const int P0 = gg << 13;
    float* yout = out + (size_t)b * 524288;
    float* mout = out + 16ull*524288 + (size_t)b * 524288;

    const size_t blkbase = (size_t)b * 513 * 2048 + (size_t)(gg * 32);
    const int n1 = tid >> 1;              // row for load A
    const int h4 = (tid & 1) * 4;         // float4 offset within the 8-float row chunk
    const int n2 = n1 + 256;              // row for load B

    float4 ar, ai, br, bi;                // prefetched spectra (rows n1, n2)
    float  nyr = 0.f, nyi = 0.f;          // Nyquist row (tid < 8)

    // ---- prologue: prefetch round 0 ----
    {
        const float* pr  = spec_re + blkbase;
        const float* pim = spec_im + blkbase;
        int offA = n1 * 2048 + h4, offB = n2 * 2048 + h4;
        ar = *(const float4*)(pr + offA);  ai = *(const float4*)(pim + offA);
        br = *(const float4*)(pr + offB);  bi = *(const float4*)(pim + offB);
        if (tid < 8) { nyr = pr[512*2048 + tid]; nyi = pim[512*2048 + tid]; }
    }

    float w[6] = {0.f, 0.f, 0.f, 0.f, 0.f, 0.f};   // rolling acc window: q = 4r+u

    for (int r = 0; r < 4; ++r) {
        BAR();   // prev gather done -> slots free; publishes s_ps on r==0
        // ---- stage prefetched regs -> LDS (compiler inserts vmcnt wait on regs) ----
        #pragma unroll
        for (int f = 0; f < 4; ++f) {
            s_slot[       (h4+f)*520 + n1] = ((const float*)&ar)[f];
            s_slot[4160 + (h4+f)*520 + n1] = ((const float*)&ai)[f];
            s_slot[       (h4+f)*520 + n2] = ((const float*)&br)[f];
            s_slot[4160 + (h4+f)*520 + n2] = ((const float*)&bi)[f];
        }
        if (tid < 8) {
            s_slot[       tid*520 + 512] = nyr;
            s_slot[4160 + tid*520 + 512] = nyi;
        }
        // ---- issue next round's loads (hidden under FFT + gather) ----
        if (r < 3) {
            const float* pr  = spec_re + blkbase + (size_t)((r+1) * 8);
            const float* pim = spec_im + blkbase + (size_t)((r+1) * 8);
            int offA = n1 * 2048 + h4, offB = n2 * 2048 + h4;
            ar = *(const float4*)(pr + offA);  ai = *(const float4*)(pim + offA);
            br = *(const float4*)(pr + offB);  bi = *(const float4*)(pim + offB);
            if (tid < 8) { nyr = pr[512*2048 + tid]; nyi = pim[512*2048 + tid]; }
        }
        BAR();   // staging visible
        // ---- FFT: wave wv handles frame f=wv, in-place in slot wv ----
        {
            const int wv = tid >> 6, l = tid & 63;
            const int a_ = l >> 3,  b_ = l & 7;
            float* Re = &s_slot[wv*520];
            float* Im = &s_slot[4160 + wv*520];
            float zr[8], zi[8];
            // Z build: Z[k] = E + i*e^{i*pi*k/512}*D, k = 64*k0 + l
            float cw = s_twzb[l].x, sw_ = s_twzb[l].y;
            const float C8 = 0.92387953251128675f, S8 = 0.38268343236508977f; // e^{i*pi/8}
            #pragma unroll
            for (int k0 = 0; k0 < 8; ++k0) {
                int k = (k0<<6) + l;
                float xkr = Re[k],     xki = Im[k];
                float xmr = Re[512-k], xmi = Im[512-k];
                if (k == 0) { xki = 0.f; xmi = 0.f; }   // zero Im(X0), Im(X512)
                float Er = 0.5f*(xkr + xmr), Ei = 0.5f*(xki - xmi);
                float Dr = 0.5f*(xkr - xmr), Di = 0.5f*(xki + xmi);
                float Or = cw*Dr - sw_*Di,  Oi = sw_*Dr + cw*Di;
                zr[k0] = Er - Oi;
                zi[k0] = Ei + Or;
                float nc = cw*C8 - sw_*S8; sw_ = sw_*C8 + cw*S8; cw = nc;
            }
            dft8(zr, zi);
            // exchange 1 (swizzled <=2-way)
            #pragma unroll
            for (int q = 0; q < 8; ++q) {
                int idx = (q<<6) + l;
                Re[idx ^ (((idx>>6)&7)<<3)] = zr[q];
                Im[idx ^ (((idx>>6)&7)<<3)] = zi[q];
            }
            #pragma unroll
            for (int q = 0; q < 8; ++q) {
                int idx = (a_<<6) + (q<<3) + b_;
                int ph = idx ^ (((idx>>6)&7)<<3);
                zr[q] = Re[ph]; zi[q] = Im[ph];
            }
            { // twiddle2: w64^{n0*k1}, incremental
                float c1 = s_tw64[a_].x, s1 = s_tw64[a_].y;
                float cr = c1, ci = s1;
                #pragma unroll
                for (int q = 1; q < 8; ++q) {
                    float tr = zr[q]*cr - zi[q]*ci;
                    zi[q] = zr[q]*ci + zi[q]*cr;
                    zr[q] = tr;
                    float nc = cr*c1 - ci*s1; ci = ci*c1 + cr*s1; cr = nc;
                }
            }
            dft8(zr, zi);
            // exchange 2
            #pragma unroll
            for (int q = 0; q < 8; ++q) {
                int idx = (b_<<6) + (q<<3) + a_;
                int ph = idx ^ (((idx>>6)&7)<<3);
                Re[ph] = zr[q]; Im[ph] = zi[q];
            }
            #pragma unroll
            for (int q = 0; q < 8; ++q) {
                int idx = (q<<6) + l;
                int ph = idx ^ (((idx>>6)&7)<<3);
                zr[q] = Re[ph]; zi[q] = Im[ph];
            }
            { // twiddle3: w512^{(n1*8+n0)*k2}, incremental
                float c1 = s_tw512[l].x, s1 = s_tw512[l].y;
                float cr = c1, ci = s1;
                #pragma unroll
                for (int q = 1; q < 8; ++q) {
                    float tr = zr[q]*cr - zi[q]*ci;
                    zi[q] = zr[q]*ci + zi[q]*cr;
                    zr[q] = tr;
                    float nc = cr*c1 - ci*s1; ci = ci*c1 + cr*s1; cr = nc;
                }
            }
            dft8(zr, zi);
            // output: lane l, reg q holds z[64q + l]; x[2n]=Re z[n], x[2n+1]=Im z[n]
            #pragma unroll
            for (int q = 0; q < 8; ++q) {
                Re[(q<<6) + l] = zr[q];
                Im[(q<<6) + l] = zi[q];
            }
        }
        BAR();   // FFT results visible
        // ---- gather this round's 8 frames into the rolling register window ----
        const int r8 = r << 3;
        #pragma unroll
        for (int u = 0; u < 6; ++u) {
            int pl = (u << 9) + tid;
            if (pl < 2816) {
                int p = (r << 11) + pl;
                int Fhi = min(r8 + 7, p >> 8);
                int Flo = max(r8, (p - 768) >> 8);
                float acc = w[u];
                for (int F = Flo; F <= Fhi; ++F) {
                    int j = p - (F << 8);
                    float v = s_slot[(j & 1)*4160 + (F - r8)*520 + (j >> 1)];
                    acc += v * s_wt[j] * s_mask[F];
                }
                w[u] = acc;
            }
        }
        // ---- retire finalized samples q = 4r..4r+3 (fire-and-forget stores) ----
        #pragma unroll
        for (int u = 0; u < 4; ++u) {
            int p = (r << 11) + (u << 9) + tid;
            retire_one(p, w[u], gg, s_wt, s_envr, s_ps, yout, mout, P0);
        }
        // shift window: q=4r+4 -> slot 0, q=4r+5 -> slot 1
        w[0] = w[4]; w[1] = w[5];
        w[2] = 0.f; w[3] = 0.f; w[4] = 0.f; w[5] = 0.f;
    }
    // final retire: q=16 (p=8192+tid), q=17 (p=8704+tid, tid<256)
    retire_one(8192 + tid, w[0], gg, s_wt, s_envr, s_ps, yout, mout, P0);
    if (tid < 256)
        retire_one(8704 + tid, w[1], gg, s_wt, s_envr, s_ps, yout, mout, P0);
}

__global__ void istft_zero(float* __restrict__ out) {
    int idx = blockIdx.x * 256 + threadIdx.x;
    if (idx >= 16*63*768) return;
    int q  = idx % 768;
    int t_ = idx / 768;
    int G  = (t_ % 63) + 1;
    int b  = t_ / 63;
    out[(size_t)b*524288 + (G << 13) + q - 384] = 0.f;
}

__global__ void istft_fixup(const float* __restrict__ mask, float* __restrict__ out) {
    int idx = blockIdx.x * 256 + threadIdx.x;
    if (idx >= 16*63*768) return;
    int q  = idx % 768;
    int t_ = idx / 768;
    int G  = (t_ % 63) + 1;
    int b  = t_ / 63;
    int P  = (G << 13) + q;
    int thi = min(2047, P >> 8);
    int tlo = (P - 768) >> 8;
    float env = 0.f, fm = 0.f;
    for (int t = tlo; t <= thi; ++t) {
        int j = P - (t << 8);
        float w = 0.5f - 0.5f * __cosf(6.2831853071795864f * (float)j * (1.0f/1024.0f));
        env += w * w;
        fm  += mask[b*2048 + t];
    }
    size_t o = (size_t)b*524288 + (size_t)(P - 384);
    out[o] = out[o] / env;
    out[16ull*524288 + o] = (fm > 0.f) ? 1.f : 0.f;
}

extern "C" void kernel_launch(void* const* d_in, const int* in_sizes, int n_in,
                              void* d_out, int out_size, void* d_ws, size_t ws_size,
                              hipStream_t stream) {
    (void)in_sizes; (void)n_in; (void)d_ws; (void)ws_size; (void)out_size;
    const float* spec_re = (const float*)d_in[0];
    const float* spec_im = (const float*)d_in[1];
    const float* mask    = (const float*)d_in[2];
    float* out = (float*)d_out;
    const int nstrip = 16*63*768;
    istft_zero <<<(nstrip + 255)/256, 256, 0, stream>>>(out);
    istft_main <<<dim3(64, 16), 512, 0, stream>>>(spec_re, spec_im, mask, out);
    istft_fixup<<<(nstrip + 255)/256, 256, 0, stream>>>(mask, out);
}

// Round 4
// 124.022 us; speedup vs baseline: 1.5111x; 1.5111x over previous
//
#include <hip/hip_runtime.h>

#define THREADS 512

// raw barrier: wait LDS ops only (NOT vmcnt) so global loads/stores stay in
// flight across the barrier. "memory" clobber pins C++ LDS access order.
#define BAR() do { asm volatile("s_waitcnt lgkmcnt(0)" ::: "memory"); \
                   __builtin_amdgcn_s_barrier();                      \
                   asm volatile("" ::: "memory"); } while (0)

// -------- radix-8 inverse DFT over register index: u[n] = sum_k v[k] e^{+2*pi*i*n*k/8}
__device__ __forceinline__ void dft8(float* vr, float* vi) {
    float t0r=vr[0]+vr[4], t0i=vi[0]+vi[4];
    float t1r=vr[0]-vr[4], t1i=vi[0]-vi[4];
    float t2r=vr[2]+vr[6], t2i=vi[2]+vi[6];
    float t3r=vr[2]-vr[6], t3i=vi[2]-vi[6];
    float t4r=vr[1]+vr[5], t4i=vi[1]+vi[5];
    float t5r=vr[1]-vr[5], t5i=vi[1]-vi[5];
    float t6r=vr[3]+vr[7], t6i=vi[3]+vi[7];
    float t7r=vr[3]-vr[7], t7i=vi[3]-vi[7];
    float e0r=t0r+t2r, e0i=t0i+t2i;
    float e1r=t1r-t3i, e1i=t1i+t3r;   // t1 + i*t3
    float e2r=t0r-t2r, e2i=t0i-t2i;
    float e3r=t1r+t3i, e3i=t1i-t3r;   // t1 - i*t3
    float o0r=t4r+t6r, o0i=t4i+t6i;
    float o1r=t5r-t7i, o1i=t5i+t7r;
    float o2r=t4r-t6r, o2i=t4i-t6i;
    float o3r=t5r+t7i, o3i=t5i-t7r;
    const float C = 0.70710678118654752f;
    float w1r = C*(o1r - o1i), w1i = C*(o1r + o1i);   // W8^1 * o1
    float w2r = -o2i,          w2i = o2r;             // i * o2
    float w3r = -C*(o3r + o3i), w3i = C*(o3r - o3i);  // W8^3 * o3
    vr[0]=e0r+o0r; vi[0]=e0i+o0i;
    vr[1]=e1r+w1r; vi[1]=e1i+w1i;
    vr[2]=e2r+w2r; vi[2]=e2i+w2i;
    vr[3]=e3r+w3r; vi[3]=e3i+w3i;
    vr[4]=e0r-o0r; vi[4]=e0i-o0i;
    vr[5]=e1r-w1r; vi[5]=e1i-w1i;
    vr[6]=e2r-w2r; vi[6]=e2i-w2i;
    vr[7]=e3r-w3r; vi[7]=e3i-w3i;
}

// retire one sample p (block-local, [0, 2816)) with accumulated value a
__device__ __forceinline__ void retire_one(int p, float a, int gg,
                                           const float* s_wt, const float* s_envr,
                                           const float* s_ps,
                                           float* yout, float* mout, int P0)
{
    bool leftStrip  = (p < 768)   && (gg != 0);
    bool rightStrip = (p >= 2048) && (gg != 255);
    if (leftStrip || rightStrip) { atomicAdd(&yout[P0 + p - 384], a); return; }
    if (gg == 0   && p < 384)  return;   // trimmed pad
    if (gg == 255 && p >= 2432) return;  // trimmed pad
    int thi = min(7, p >> 8);
    int tlo = max(0, (p - 768) >> 8);
    float fm = s_ps[thi + 1] - s_ps[tlo];
    float envr;
    if ((gg == 0 && p < 768) || (gg == 255 && p >= 2048)) {
        float e = 0.f;
        for (int t = tlo; t <= thi; ++t) {
            float w = s_wt[p - (t << 8)] * 512.0f;
            e += w * w;
        }
        envr = 1.0f / e;
    } else {
        envr = s_envr[p & 255];          // periodic interior, reciprocal
    }
    int s = P0 + p - 384;
    yout[s] = a * envr;
    mout[s] = (fm > 0.f) ? 1.0f : 0.0f;
}

// one block = (batch b, 8 frames). 512 threads = 8 waves, one FFT per wave,
// single phase: stage -> BAR -> FFT -> BAR -> gather+retire. 2 barriers total.
__global__ __launch_bounds__(512, 6) void istft_main(const float* __restrict__ spec_re,
                                                     const float* __restrict__ spec_im,
                                                     const float* __restrict__ mask,
                                                     float* __restrict__ out)
{
    const int gg  = blockIdx.x;   // frame-group 0..255 (frames [8g, 8g+8))
    const int b   = blockIdx.y;   // batch 0..15
    const int tid = threadIdx.x;

    __shared__ float  s_slot[8352];   // 8 slots x 522: re [0,4176), im [4176,8352)
    __shared__ float  s_wt[1024];     // hann(j)/512
    __shared__ float  s_envr[256];    // 1 / (periodic fold of hann^2)
    __shared__ float  s_mask[8];      // mask[b, 8g .. 8g+8)
    __shared__ float  s_ps[9];        // prefix sums of s_mask
    __shared__ float2 s_twzb[64];     // e^{i*pi*l/512}
    __shared__ float2 s_tw64[8];      // e^{2*pi*i*a/64}
    __shared__ float2 s_tw512[64];    // e^{2*pi*i*l/512}

    // ---- tables ----
    for (int i = tid; i < 1024; i += THREADS) {
        float w = 0.5f - 0.5f * cosf(6.2831853071795864f * (float)i * (1.0f/1024.0f));
        s_wt[i] = w * (1.0f/512.0f);
    }
    if (tid < 256) {
        float e = 0.f;
        for (int k = 0; k < 4; ++k) {
            float w = 0.5f - 0.5f * cosf(6.2831853071795864f * (float)(tid + (k<<8)) * (1.0f/1024.0f));
            e += w * w;
        }
        s_envr[tid] = 1.0f / e;
    }
    if (tid < 64) {
        float a1 = 3.1415926535897932f * (float)tid * (1.0f/512.0f);
        s_twzb[tid] = make_float2(cosf(a1), sinf(a1));
        float a2 = 6.2831853071795864f * (float)tid * (1.0f/512.0f);
        s_tw512[tid] = make_float2(cosf(a2), sinf(a2));
    }
    if (tid < 8) {
        float a = 6.2831853071795864f * (float)tid * (1.0f/64.0f);
        s_tw64[tid] = make_float2(cosf(a), sinf(a));
        s_mask[tid] = mask[b*2048 + gg*8 + tid];
    }

    // ---- stage spectra: 513 rows x 8 frames, re+im (coalesced 32B row chunks) ----
    const size_t base = (size_t)b * 513 * 2048 + (size_t)(gg * 8);
    for (int i = tid; i < 1026; i += THREADS) {     // 513 rows x 2 float4
        int n = i >> 1, c = i & 1;
        size_t off = base + (size_t)n * 2048 + (size_t)(c * 4);
        float4 vr = *(const float4*)(spec_re + off);
        float4 vi = *(const float4*)(spec_im + off);
        #pragma unroll
        for (int f = 0; f < 4; ++f) {
            s_slot[       (c*4+f)*522 + n] = ((const float*)&vr)[f];
            s_slot[4176 + (c*4+f)*522 + n] = ((const float*)&vi)[f];
        }
    }
    if (tid == 0) {                    // tiny serial prefix over 8 mask values
        float acc = 0.f;
        s_ps[0] = 0.f;
        for (int i = 0; i < 8; ++i) { acc += s_mask[i]; s_ps[i+1] = acc; }
    }
    BAR();   // staging + tables visible

    // ---- FFT: wave wv handles frame f=wv, in-place in slot wv ----
    {
        const int wv = tid >> 6, l = tid & 63;
        const int a_ = l >> 3,  b_ = l & 7;
        float* Re = &s_slot[wv*522];
        float* Im = &s_slot[4176 + wv*522];
        float zr[8], zi[8];
        // Z build: Z[k] = E + i*e^{i*pi*k/512}*D, k = 64*k0 + l
        float cw = s_twzb[l].x, sw_ = s_twzb[l].y;
        const float C8 = 0.92387953251128675f, S8 = 0.38268343236508977f; // e^{i*pi/8}
        #pragma unroll
        for (int k0 = 0; k0 < 8; ++k0) {
            int k = (k0<<6) + l;
            float xkr = Re[k],     xki = Im[k];
            float xmr = Re[512-k], xmi = Im[512-k];
            if (k == 0) { xki = 0.f; xmi = 0.f; }   // zero Im(X0), Im(X512)
            float Er = 0.5f*(xkr + xmr), Ei = 0.5f*(xki - xmi);
            float Dr = 0.5f*(xkr - xmr), Di = 0.5f*(xki + xmi);
            float Or = cw*Dr - sw_*Di,  Oi = sw_*Dr + cw*Di;
            zr[k0] = Er - Oi;
            zi[k0] = Ei + Or;
            float nc = cw*C8 - sw_*S8; sw_ = sw_*C8 + cw*S8; cw = nc;
        }
        dft8(zr, zi);
        // exchange 1 (XOR-swizzled, <=2-way)
        #pragma unroll
        for (int q = 0; q < 8; ++q) {
            int idx = (q<<6) + l;
            Re[idx ^ (((idx>>6)&7)<<3)] = zr[q];
            Im[idx ^ (((idx>>6)&7)<<3)] = zi[q];
        }
        #pragma unroll
        for (int q = 0; q < 8; ++q) {
            int idx = (a_<<6) + (q<<3) + b_;
            int ph = idx ^ (((idx>>6)&7)<<3);
            zr[q] = Re[ph]; zi[q] = Im[ph];
        }
        { // twiddle2: w64^{n0*k1}, incremental
            float c1 = s_tw64[a_].x, s1 = s_tw64[a_].y;
            float cr = c1, ci = s1;
            #pragma unroll
            for (int q = 1; q < 8; ++q) {
                float tr = zr[q]*cr - zi[q]*ci;
                zi[q] = zr[q]*ci + zi[q]*cr;
                zr[q] = tr;
                float nc = cr*c1 - ci*s1; ci = ci*c1 + cr*s1; cr = nc;
            }
        }
        dft8(zr, zi);
        // exchange 2
        #pragma unroll
        for (int q = 0; q < 8; ++q) {
            int idx = (b_<<6) + (q<<3) + a_;
            int ph = idx ^ (((idx>>6)&7)<<3);
            Re[ph] = zr[q]; Im[ph] = zi[q];
        }
        #pragma unroll
        for (int q = 0; q < 8; ++q) {
            int idx = (q<<6) + l;
            int ph = idx ^ (((idx>>6)&7)<<3);
            zr[q] = Re[ph]; zi[q] = Im[ph];
        }
        { // twiddle3: w512^{(n1*8+n0)*k2}, incremental
            float c1 = s_tw512[l].x, s1 = s_tw512[l].y;
            float cr = c1, ci = s1;
            #pragma unroll
            for (int q = 1; q < 8; ++q) {
                float tr = zr[q]*cr - zi[q]*ci;
                zi[q] = zr[q]*ci + zi[q]*cr;
                zr[q] = tr;
                float nc = cr*c1 - ci*s1; ci = ci*c1 + cr*s1; cr = nc;
            }
        }
        dft8(zr, zi);
        // output: lane l, reg q holds z[64q + l]; x[2n]=Re z[n], x[2n+1]=Im z[n]
        #pragma unroll
        for (int q = 0; q < 8; ++q) {
            Re[(q<<6) + l] = zr[q];
            Im[(q<<6) + l] = zi[q];
        }
    }
    BAR();   // FFT results visible

    // ---- gather + retire (fused): thread owns p = q*512 + tid, p < 2816 ----
    const int P0 = gg << 11;
    float* yout = out + (size_t)b * 524288;
    float* mout = out + 16ull*524288 + (size_t)b * 524288;
    #pragma unroll
    for (int q = 0; q < 6; ++q) {
        int p = (q << 9) + tid;
        if (p < 2816) {
            int Fhi = min(7, p >> 8);
            int Flo = max(0, (p - 768) >> 8);
            float acc = 0.f;
            for (int F = Flo; F <= Fhi; ++F) {
                int j = p - (F << 8);
                acc += s_slot[(j & 1)*4176 + F*522 + (j >> 1)] * s_wt[j] * s_mask[F];
            }
            retire_one(p, acc, gg, s_wt, s_envr, s_ps, yout, mout, P0);
        }
    }
}

__global__ void istft_zero(float* __restrict__ out) {
    int idx = blockIdx.x * 256 + threadIdx.x;
    if (idx >= 16*255*768) return;
    int q  = idx % 768;
    int t_ = idx / 768;
    int G  = (t_ % 255) + 1;
    int b  = t_ / 255;
    out[(size_t)b*524288 + (G << 11) + q - 384] = 0.f;
}

__global__ void istft_fixup(const float* __restrict__ mask, float* __restrict__ out) {
    int idx = blockIdx.x * 256 + threadIdx.x;
    if (idx >= 16*255*768) return;
    int q  = idx % 768;
    int t_ = idx / 768;
    int G  = (t_ % 255) + 1;
    int b  = t_ / 255;
    int P  = (G << 11) + q;
    int thi = min(2047, P >> 8);
    int tlo = (P - 768) >> 8;
    float env = 0.f, fm = 0.f;
    for (int t = tlo; t <= thi; ++t) {
        int j = P - (t << 8);
        float w = 0.5f - 0.5f * __cosf(6.2831853071795864f * (float)j * (1.0f/1024.0f));
        env += w * w;
        fm  += mask[b*2048 + t];
    }
    size_t o = (size_t)b*524288 + (size_t)(P - 384);
    out[o] = out[o] / env;
    out[16ull*524288 + o] = (fm > 0.f) ? 1.f : 0.f;
}

extern "C" void kernel_launch(void* const* d_in, const int* in_sizes, int n_in,
                              void* d_out, int out_size, void* d_ws, size_t ws_size,
                              hipStream_t stream) {
    (void)in_sizes; (void)n_in; (void)d_ws; (void)ws_size; (void)out_size;
    const float* spec_re = (const float*)d_in[0];
    const float* spec_im = (const float*)d_in[1];
    const float* mask    = (const float*)d_in[2];
    float* out = (float*)d_out;
    const int nstrip = 16*255*768;
    istft_zero <<<(nstrip + 255)/256, 256, 0, stream>>>(out);
    istft_main <<<dim3(256, 16), 512, 0, stream>>>(spec_re, spec_im, mask, out);
    istft_fixup<<<(nstrip + 255)/256, 256, 0, stream>>>(mask, out);
}

// Round 5
// 119.497 us; speedup vs baseline: 1.5684x; 1.0379x over previous
//
#include <hip/hip_runtime.h>

#define THREADS 512

// raw barrier: wait LDS ops only (NOT vmcnt) so global loads/stores stay in
// flight across the barrier. "memory" clobber pins C++ LDS access order.
#define BAR() do { asm volatile("s_waitcnt lgkmcnt(0)" ::: "memory"); \
                   __builtin_amdgcn_s_barrier();                      \
                   asm volatile("" ::: "memory"); } while (0)

// -------- radix-8 inverse DFT over register index: u[n] = sum_k v[k] e^{+2*pi*i*n*k/8}
__device__ __forceinline__ void dft8(float* vr, float* vi) {
    float t0r=vr[0]+vr[4], t0i=vi[0]+vi[4];
    float t1r=vr[0]-vr[4], t1i=vi[0]-vi[4];
    float t2r=vr[2]+vr[6], t2i=vi[2]+vi[6];
    float t3r=vr[2]-vr[6], t3i=vi[2]-vi[6];
    float t4r=vr[1]+vr[5], t4i=vi[1]+vi[5];
    float t5r=vr[1]-vr[5], t5i=vi[1]-vi[5];
    float t6r=vr[3]+vr[7], t6i=vi[3]+vi[7];
    float t7r=vr[3]-vr[7], t7i=vi[3]-vi[7];
    float e0r=t0r+t2r, e0i=t0i+t2i;
    float e1r=t1r-t3i, e1i=t1i+t3r;   // t1 + i*t3
    float e2r=t0r-t2r, e2i=t0i-t2i;
    float e3r=t1r+t3i, e3i=t1i-t3r;   // t1 - i*t3
    float o0r=t4r+t6r, o0i=t4i+t6i;
    float o1r=t5r-t7i, o1i=t5i+t7r;
    float o2r=t4r-t6r, o2i=t4i-t6i;
    float o3r=t5r+t7i, o3i=t5i-t7r;
    const float C = 0.70710678118654752f;
    float w1r = C*(o1r - o1i), w1i = C*(o1r + o1i);   // W8^1 * o1
    float w2r = -o2i,          w2i = o2r;             // i * o2
    float w3r = -C*(o3r + o3i), w3i = C*(o3r - o3i);  // W8^3 * o3
    vr[0]=e0r+o0r; vi[0]=e0i+o0i;
    vr[1]=e1r+w1r; vi[1]=e1i+w1i;
    vr[2]=e2r+w2r; vi[2]=e2i+w2i;
    vr[3]=e3r+w3r; vi[3]=e3i+w3i;
    vr[4]=e0r-o0r; vi[4]=e0i-o0i;
    vr[5]=e1r-w1r; vi[5]=e1i-w1i;
    vr[6]=e2r-w2r; vi[6]=e2i-w2i;
    vr[7]=e3r-w3r; vi[7]=e3i-w3i;
}

// retire one BOUNDARY sample p (block-local) with accumulated value a
__device__ __forceinline__ void retire_one(int p, float a, int gg,
                                           const float* s_wt, const float* s_envr,
                                           const float* s_ps,
                                           float* yout, float* mout, int P0)
{
    bool leftStrip  = (p < 768)   && (gg != 0);
    bool rightStrip = (p >= 2048) && (gg != 255);
    if (leftStrip || rightStrip) { atomicAdd(&yout[P0 + p - 384], a); return; }
    if (gg == 0   && p < 384)  return;   // trimmed pad
    if (gg == 255 && p >= 2432) return;  // trimmed pad
    int thi = min(7, p >> 8);
    int tlo = max(0, (p - 768) >> 8);
    float fm = s_ps[thi + 1] - s_ps[tlo];
    float envr;
    if ((gg == 0 && p < 768) || (gg == 255 && p >= 2048)) {
        float e = 0.f;
        for (int t = tlo; t <= thi; ++t) {
            float w = s_wt[p - (t << 8)] * 512.0f;
            e += w * w;
        }
        envr = 1.0f / e;
    } else {
        envr = s_envr[p & 255];          // periodic interior, reciprocal
    }
    int s = P0 + p - 384;
    yout[s] = a * envr;
    mout[s] = (fm > 0.f) ? 1.0f : 0.0f;
}

// one block = (batch b, 8 frames). 512 threads = 8 waves, one FFT per wave,
// single phase: load -> tables -> stage -> BAR -> FFT -> BAR -> gather+retire.
__global__ __launch_bounds__(512, 6) void istft_main(const float* __restrict__ spec_re,
                                                     const float* __restrict__ spec_im,
                                                     const float* __restrict__ mask,
                                                     float* __restrict__ out)
{
    const int gg  = blockIdx.x;   // frame-group 0..255 (frames [8g, 8g+8))
    const int b   = blockIdx.y;   // batch 0..15
    const int tid = threadIdx.x;

    __shared__ float  s_slot[8352];   // 8 slots x 522: re [0,4176), im [4176,8352)
    __shared__ float  s_wt[1024];     // hann(j)/512
    __shared__ float  s_envr[256];    // 1 / (periodic fold of hann^2)
    __shared__ float  s_mask[8];      // mask[b, 8g .. 8g+8)
    __shared__ float  s_ps[9];        // prefix sums of s_mask
    __shared__ float2 s_twzb[64];     // e^{i*pi*l/512}
    __shared__ float2 s_tw64[8];      // e^{2*pi*i*a/64}
    __shared__ float2 s_tw512[64];    // e^{2*pi*i*l/512}

    // ---- issue global loads FIRST (latency hides under table build) ----
    const size_t base = (size_t)b * 513 * 2048 + (size_t)(gg * 8);
    // item i (0..1025): row n=i>>1, half c=i&1 -> float4 at (n, c*4)
    const int i0 = tid, i1 = tid + 512;
    float4 vr0, vi0, vr1, vi1, vr2, vi2;
    float mval = 0.f;
    {
        size_t off0 = base + (size_t)(i0 >> 1) * 2048 + (size_t)((i0 & 1) * 4);
        vr0 = *(const float4*)(spec_re + off0);
        vi0 = *(const float4*)(spec_im + off0);
        size_t off1 = base + (size_t)(i1 >> 1) * 2048 + (size_t)((i1 & 1) * 4);
        vr1 = *(const float4*)(spec_re + off1);
        vi1 = *(const float4*)(spec_im + off1);
        if (tid < 2) {   // leftover items 1024,1025
            int i2 = 1024 + tid;
            size_t off2 = base + (size_t)(i2 >> 1) * 2048 + (size_t)((i2 & 1) * 4);
            vr2 = *(const float4*)(spec_re + off2);
            vi2 = *(const float4*)(spec_im + off2);
        }
        if (tid < 8) mval = mask[b*2048 + gg*8 + tid];
    }

    // ---- tables (fast hardware trig; accuracy ~1e-5 << 2e-2 threshold) ----
    for (int i = tid; i < 1024; i += THREADS) {
        float w = 0.5f - 0.5f * __cosf(6.2831853071795864f * (float)i * (1.0f/1024.0f));
        s_wt[i] = w * (1.0f/512.0f);
    }
    if (tid < 256) {
        float e = 0.f;
        #pragma unroll
        for (int k = 0; k < 4; ++k) {
            float w = 0.5f - 0.5f * __cosf(6.2831853071795864f * (float)(tid + (k<<8)) * (1.0f/1024.0f));
            e += w * w;
        }
        s_envr[tid] = 1.0f / e;
    }
    if (tid < 64) {
        float s1, c1, s2, c2;
        __sincosf(3.1415926535897932f * (float)tid * (1.0f/512.0f), &s1, &c1);
        s_twzb[tid] = make_float2(c1, s1);
        __sincosf(6.2831853071795864f * (float)tid * (1.0f/512.0f), &s2, &c2);
        s_tw512[tid] = make_float2(c2, s2);
    }
    if (tid < 8) {
        float s3, c3;
        __sincosf(6.2831853071795864f * (float)tid * (1.0f/64.0f), &s3, &c3);
        s_tw64[tid] = make_float2(c3, s3);
        s_mask[tid] = mval;
    }

    // ---- stage loaded registers -> LDS (transpose to frame-major) ----
    {
        int n0 = i0 >> 1, c0 = (i0 & 1) * 4;
        #pragma unroll
        for (int f = 0; f < 4; ++f) {
            s_slot[       (c0+f)*522 + n0] = ((const float*)&vr0)[f];
            s_slot[4176 + (c0+f)*522 + n0] = ((const float*)&vi0)[f];
        }
        int n1 = i1 >> 1, c1 = (i1 & 1) * 4;
        #pragma unroll
        for (int f = 0; f < 4; ++f) {
            s_slot[       (c1+f)*522 + n1] = ((const float*)&vr1)[f];
            s_slot[4176 + (c1+f)*522 + n1] = ((const float*)&vi1)[f];
        }
        if (tid < 2) {
            int i2 = 1024 + tid;
            int n2 = i2 >> 1, c2 = (i2 & 1) * 4;
            #pragma unroll
            for (int f = 0; f < 4; ++f) {
                s_slot[       (c2+f)*522 + n2] = ((const float*)&vr2)[f];
                s_slot[4176 + (c2+f)*522 + n2] = ((const float*)&vi2)[f];
            }
        }
    }
    if (tid == 0) {                    // tiny serial prefix over 8 mask values
        float acc = 0.f;
        s_ps[0] = 0.f;
        #pragma unroll
        for (int i = 0; i < 8; ++i) { acc += s_mask[i]; s_ps[i+1] = acc; }
    }
    BAR();   // staging + tables visible

    // ---- FFT: wave wv handles frame f=wv, in-place in slot wv ----
    {
        const int wv = tid >> 6, l = tid & 63;
        const int a_ = l >> 3,  b_ = l & 7;
        float* Re = &s_slot[wv*522];
        float* Im = &s_slot[4176 + wv*522];
        float zr[8], zi[8];
        // Z build: Z[k] = E + i*e^{i*pi*k/512}*D, k = 64*k0 + l
        float cw = s_twzb[l].x, sw_ = s_twzb[l].y;
        const float C8 = 0.92387953251128675f, S8 = 0.38268343236508977f; // e^{i*pi/8}
        #pragma unroll
        for (int k0 = 0; k0 < 8; ++k0) {
            int k = (k0<<6) + l;
            float xkr = Re[k],     xki = Im[k];
            float xmr = Re[512-k], xmi = Im[512-k];
            if (k == 0) { xki = 0.f; xmi = 0.f; }   // zero Im(X0), Im(X512)
            float Er = 0.5f*(xkr + xmr), Ei = 0.5f*(xki - xmi);
            float Dr = 0.5f*(xkr - xmr), Di = 0.5f*(xki + xmi);
            float Or = cw*Dr - sw_*Di,  Oi = sw_*Dr + cw*Di;
            zr[k0] = Er - Oi;
            zi[k0] = Ei + Or;
            float nc = cw*C8 - sw_*S8; sw_ = sw_*C8 + cw*S8; cw = nc;
        }
        dft8(zr, zi);
        // exchange 1 (XOR-swizzled, <=2-way)
        #pragma unroll
        for (int q = 0; q < 8; ++q) {
            int idx = (q<<6) + l;
            Re[idx ^ (((idx>>6)&7)<<3)] = zr[q];
            Im[idx ^ (((idx>>6)&7)<<3)] = zi[q];
        }
        #pragma unroll
        for (int q = 0; q < 8; ++q) {
            int idx = (a_<<6) + (q<<3) + b_;
            int ph = idx ^ (((idx>>6)&7)<<3);
            zr[q] = Re[ph]; zi[q] = Im[ph];
        }
        { // twiddle2: w64^{n0*k1}, incremental
            float c1 = s_tw64[a_].x, s1 = s_tw64[a_].y;
            float cr = c1, ci = s1;
            #pragma unroll
            for (int q = 1; q < 8; ++q) {
                float tr = zr[q]*cr - zi[q]*ci;
                zi[q] = zr[q]*ci + zi[q]*cr;
                zr[q] = tr;
                float nc = cr*c1 - ci*s1; ci = ci*c1 + cr*s1; cr = nc;
            }
        }
        dft8(zr, zi);
        // exchange 2
        #pragma unroll
        for (int q = 0; q < 8; ++q) {
            int idx = (b_<<6) + (q<<3) + a_;
            int ph = idx ^ (((idx>>6)&7)<<3);
            Re[ph] = zr[q]; Im[ph] = zi[q];
        }
        #pragma unroll
        for (int q = 0; q < 8; ++q) {
            int idx = (q<<6) + l;
            int ph = idx ^ (((idx>>6)&7)<<3);
            zr[q] = Re[ph]; zi[q] = Im[ph];
        }
        { // twiddle3: w512^{(n1*8+n0)*k2}, incremental
            float c1 = s_tw512[l].x, s1 = s_tw512[l].y;
            float cr = c1, ci = s1;
            #pragma unroll
            for (int q = 1; q < 8; ++q) {
                float tr = zr[q]*cr - zi[q]*ci;
                zi[q] = zr[q]*ci + zi[q]*cr;
                zr[q] = tr;
                float nc = cr*c1 - ci*s1; ci = ci*c1 + cr*s1; cr = nc;
            }
        }
        dft8(zr, zi);
        // output: lane l, reg q holds z[64q + l]; x[2n]=Re z[n], x[2n+1]=Im z[n]
        #pragma unroll
        for (int q = 0; q < 8; ++q) {
            Re[(q<<6) + l] = zr[q];
            Im[(q<<6) + l] = zi[q];
        }
    }
    BAR();   // FFT results visible

    // ---- gather + retire ----
    const int P0 = gg << 11;
    float* yout = out + (size_t)b * 524288;
    float* mout = out + 16ull*524288 + (size_t)b * 524288;

    // interior samples p in [768, 2048): exactly 4 terms, periodic env, no branches
    // q=1 (tid>=256), q=2, q=3
    {
        #pragma unroll
        for (int q = 1; q < 4; ++q) {
            int p = (q << 9) + tid;
            if (q > 1 || tid >= 256) {
                int F0 = (p >> 8) - 3;
                float acc = 0.f;
                #pragma unroll
                for (int u = 0; u < 4; ++u) {
                    int F = F0 + u;
                    int j = p - (F << 8);
                    acc += s_slot[(j & 1)*4176 + F*522 + (j >> 1)] * s_wt[j] * s_mask[F];
                }
                float fm = s_ps[(p >> 8) + 1] - s_ps[F0];
                int s = P0 + p - 384;
                yout[s] = acc * s_envr[p & 255];
                mout[s] = (fm > 0.f) ? 1.0f : 0.0f;
            }
        }
    }
    // boundary samples: q=0 (p<512), q=1 low half (512..767), q=4, q=5
    {
        #pragma unroll
        for (int v = 0; v < 3; ++v) {
            int p = (v == 0) ? tid : ((v == 1) ? (512 + tid) : ((4 << 9) + tid));
            bool active = (v == 0) || (v == 1 && tid < 256) || (v == 2);
            if (active) {
                int Fhi = min(7, p >> 8);
                int Flo = max(0, (p - 768) >> 8);
                float acc = 0.f;
                for (int F = Flo; F <= Fhi; ++F) {
                    int j = p - (F << 8);
                    acc += s_slot[(j & 1)*4176 + F*522 + (j >> 1)] * s_wt[j] * s_mask[F];
                }
                retire_one(p, acc, gg, s_wt, s_envr, s_ps, yout, mout, P0);
            }
        }
        // q=5: p in [2560, 2816) -> tid < 256
        if (tid < 256) {
            int p = 2560 + tid;
            int Flo = (p - 768) >> 8;   // = 7
            float acc = 0.f;
            for (int F = Flo; F < 8; ++F) {
                int j = p - (F << 8);
                acc += s_slot[(j & 1)*4176 + F*522 + (j >> 1)] * s_wt[j] * s_mask[F];
            }
            retire_one(p, acc, gg, s_wt, s_envr, s_ps, yout, mout, P0);
        }
    }
}

__global__ void istft_zero(float* __restrict__ out) {
    int idx = blockIdx.x * 256 + threadIdx.x;
    if (idx >= 16*255*768) return;
    int q  = idx % 768;
    int t_ = idx / 768;
    int G  = (t_ % 255) + 1;
    int b  = t_ / 255;
    out[(size_t)b*524288 + (G << 11) + q - 384] = 0.f;
}

__global__ void istft_fixup(const float* __restrict__ mask, float* __restrict__ out) {
    int idx = blockIdx.x * 256 + threadIdx.x;
    if (idx >= 16*255*768) return;
    int q  = idx % 768;
    int t_ = idx / 768;
    int G  = (t_ % 255) + 1;
    int b  = t_ / 255;
    int P  = (G << 11) + q;
    int thi = min(2047, P >> 8);
    int tlo = (P - 768) >> 8;
    float env = 0.f, fm = 0.f;
    for (int t = tlo; t <= thi; ++t) {
        int j = P - (t << 8);
        float w = 0.5f - 0.5f * __cosf(6.2831853071795864f * (float)j * (1.0f/1024.0f));
        env += w * w;
        fm  += mask[b*2048 + t];
    }
    size_t o = (size_t)b*524288 + (size_t)(P - 384);
    out[o] = out[o] / env;
    out[16ull*524288 + o] = (fm > 0.f) ? 1.f : 0.f;
}

extern "C" void kernel_launch(void* const* d_in, const int* in_sizes, int n_in,
                              void* d_out, int out_size, void* d_ws, size_t ws_size,
                              hipStream_t stream) {
    (void)in_sizes; (void)n_in; (void)d_ws; (void)ws_size; (void)out_size;
    const float* spec_re = (const float*)d_in[0];
    const float* spec_im = (const float*)d_in[1];
    const float* mask    = (const float*)d_in[2];
    float* out = (float*)d_out;
    const int nstrip = 16*255*768;
    istft_zero <<<(nstrip + 255)/256, 256, 0, stream>>>(out);
    istft_main <<<dim3(256, 16), 512, 0, stream>>>(spec_re, spec_im, mask, out);
    istft_fixup<<<(nstrip + 255)/256, 256, 0, stream>>>(mask, out);
}

// Round 6
// 112.489 us; speedup vs baseline: 1.6661x; 1.0623x over previous
//
#include <hip/hip_runtime.h>

#define THREADS 512
#define STRIDE  516   // float2 units per slot (513 used + pad)

// raw barrier: wait LDS ops only (NOT vmcnt) so global loads/stores stay in
// flight across the barrier. "memory" clobber pins C++ LDS access order.
#define BAR() do { asm volatile("s_waitcnt lgkmcnt(0)" ::: "memory"); \
                   __builtin_amdgcn_s_barrier();                      \
                   asm volatile("" ::: "memory"); } while (0)

// XOR swizzle on complex-element index; bijective on [0,512), fixes 512.
__device__ __forceinline__ int swz(int i) { return i ^ (((i >> 6) & 7) << 3); }

// -------- radix-8 inverse DFT over register index: u[n] = sum_k v[k] e^{+2*pi*i*n*k/8}
__device__ __forceinline__ void dft8(float* vr, float* vi) {
    float t0r=vr[0]+vr[4], t0i=vi[0]+vi[4];
    float t1r=vr[0]-vr[4], t1i=vi[0]-vi[4];
    float t2r=vr[2]+vr[6], t2i=vi[2]+vi[6];
    float t3r=vr[2]-vr[6], t3i=vi[2]-vi[6];
    float t4r=vr[1]+vr[5], t4i=vi[1]+vi[5];
    float t5r=vr[1]-vr[5], t5i=vi[1]-vi[5];
    float t6r=vr[3]+vr[7], t6i=vi[3]+vi[7];
    float t7r=vr[3]-vr[7], t7i=vi[3]-vi[7];
    float e0r=t0r+t2r, e0i=t0i+t2i;
    float e1r=t1r-t3i, e1i=t1i+t3r;   // t1 + i*t3
    float e2r=t0r-t2r, e2i=t0i-t2i;
    float e3r=t1r+t3i, e3i=t1i-t3r;   // t1 - i*t3
    float o0r=t4r+t6r, o0i=t4i+t6i;
    float o1r=t5r-t7i, o1i=t5i+t7r;
    float o2r=t4r-t6r, o2i=t4i-t6i;
    float o3r=t5r+t7i, o3i=t5i-t7r;
    const float C = 0.70710678118654752f;
    float w1r = C*(o1r - o1i), w1i = C*(o1r + o1i);   // W8^1 * o1
    float w2r = -o2i,          w2i = o2r;             // i * o2
    float w3r = -C*(o3r + o3i), w3i = C*(o3r - o3i);  // W8^3 * o3
    vr[0]=e0r+o0r; vi[0]=e0i+o0i;
    vr[1]=e1r+w1r; vi[1]=e1i+w1i;
    vr[2]=e2r+w2r; vi[2]=e2i+w2i;
    vr[3]=e3r+w3r; vi[3]=e3i+w3i;
    vr[4]=e0r-o0r; vi[4]=e0i-o0i;
    vr[5]=e1r-w1r; vi[5]=e1i-w1i;
    vr[6]=e2r-w2r; vi[6]=e2i-w2i;
    vr[7]=e3r-w3r; vi[7]=e3i-w3i;
}

// one block = (batch b, 8 frames). 512 threads = 8 waves, one FFT per wave.
// load -> tables -> stage(mask-folded, complex-interleaved) -> BAR -> FFT -> BAR -> gather.
template<bool USE_WS>
__global__ __launch_bounds__(512, 6) void istft_main(const float* __restrict__ spec_re,
                                                     const float* __restrict__ spec_im,
                                                     const float* __restrict__ mask,
                                                     float* __restrict__ out,
                                                     float* __restrict__ wsL,
                                                     float* __restrict__ wsR)
{
    const int gg  = blockIdx.x;   // frame-group 0..255 (frames [8g, 8g+8))
    const int b   = blockIdx.y;   // batch 0..15
    const int tid = threadIdx.x;

    __shared__ float2 s_slot[8*STRIDE]; // 8 slots of 513 complex (swizzled idx)
    __shared__ float  s_wt[1024];       // hann(j)/512
    __shared__ float  s_envr[256];      // 1 / (periodic fold of hann^2)
    __shared__ float  s_maskx[14];      // mask frames gg*8-3 .. gg*8+10 (OOR = 0)
    __shared__ float  s_ps[15];         // prefix sums of s_maskx
    __shared__ float2 s_twzb[64];       // e^{i*pi*l/512}
    __shared__ float2 s_tw64[8];        // e^{2*pi*i*a/64}
    __shared__ float2 s_tw512[64];      // e^{2*pi*i*l/512}

    // ---- issue global loads FIRST (latency hides under table build) ----
    const size_t base = (size_t)b * 513 * 2048 + (size_t)(gg * 8);
    const int i0 = tid, i1 = tid + 512;
    float4 vr0, vi0, vr1, vi1, vr2, vi2;
    float4 mk;
    float mxv = 0.f;
    {
        size_t off0 = base + (size_t)(i0 >> 1) * 2048 + (size_t)((i0 & 1) * 4);
        vr0 = *(const float4*)(spec_re + off0);
        vi0 = *(const float4*)(spec_im + off0);
        size_t off1 = base + (size_t)(i1 >> 1) * 2048 + (size_t)((i1 & 1) * 4);
        vr1 = *(const float4*)(spec_re + off1);
        vi1 = *(const float4*)(spec_im + off1);
        if (tid < 2) {
            int i2 = 1024 + tid;
            size_t off2 = base + (size_t)(i2 >> 1) * 2048 + (size_t)((i2 & 1) * 4);
            vr2 = *(const float4*)(spec_re + off2);
            vi2 = *(const float4*)(spec_im + off2);
        }
        mk = *(const float4*)(mask + b*2048 + gg*8 + ((tid & 1) << 2));
        if (tid < 14) {
            int gf = gg*8 - 3 + tid;
            mxv = (gf >= 0 && gf < 2048) ? mask[b*2048 + gf] : 0.f;
        }
    }

    // ---- tables (hardware trig) ----
    for (int i = tid; i < 1024; i += THREADS) {
        float w = 0.5f - 0.5f * __cosf(6.2831853071795864f * (float)i * (1.0f/1024.0f));
        s_wt[i] = w * (1.0f/512.0f);
    }
    if (tid < 256) {
        float e = 0.f;
        #pragma unroll
        for (int k = 0; k < 4; ++k) {
            float w = 0.5f - 0.5f * __cosf(6.2831853071795864f * (float)(tid + (k<<8)) * (1.0f/1024.0f));
            e += w * w;
        }
        s_envr[tid] = 1.0f / e;
    }
    if (tid < 64) {
        float s1, c1, s2, c2;
        __sincosf(3.1415926535897932f * (float)tid * (1.0f/512.0f), &s1, &c1);
        s_twzb[tid] = make_float2(c1, s1);
        __sincosf(6.2831853071795864f * (float)tid * (1.0f/512.0f), &s2, &c2);
        s_tw512[tid] = make_float2(c2, s2);
    }
    if (tid < 8) {
        float s3, c3;
        __sincosf(6.2831853071795864f * (float)tid * (1.0f/64.0f), &s3, &c3);
        s_tw64[tid] = make_float2(c3, s3);
    }
    if (tid < 14) s_maskx[tid] = mxv;

    // ---- stage (mask folded into spectrum; complex-interleaved, swizzled) ----
    {
        const float* mp = (const float*)&mk;
        int n0 = i0 >> 1, c0 = (i0 & 1) * 4, p0 = swz(n0);
        #pragma unroll
        for (int f = 0; f < 4; ++f)
            s_slot[(c0+f)*STRIDE + p0] = make_float2(((const float*)&vr0)[f]*mp[f],
                                                     ((const float*)&vi0)[f]*mp[f]);
        int n1 = i1 >> 1, c1 = (i1 & 1) * 4, p1 = swz(n1);
        #pragma unroll
        for (int f = 0; f < 4; ++f)
            s_slot[(c1+f)*STRIDE + p1] = make_float2(((const float*)&vr1)[f]*mp[f],
                                                     ((const float*)&vi1)[f]*mp[f]);
        if (tid < 2) {
            int c2 = (tid & 1) * 4;   // row 512 (Nyquist), swz(512)=512
            #pragma unroll
            for (int f = 0; f < 4; ++f)
                s_slot[(c2+f)*STRIDE + 512] = make_float2(((const float*)&vr2)[f]*mp[f],
                                                          ((const float*)&vi2)[f]*mp[f]);
        }
    }
    if (tid == 0) {
        float acc = 0.f;
        s_ps[0] = 0.f;
        #pragma unroll
        for (int i = 0; i < 14; ++i) { acc += s_maskx[i]; s_ps[i+1] = acc; }
    }
    BAR();   // staging + tables visible

    // ---- FFT: wave wv handles frame f=wv, in-place in slot wv ----
    {
        const int wv = tid >> 6, l = tid & 63;
        const int a_ = l >> 3,  b_ = l & 7;
        float2* Sl = &s_slot[wv*STRIDE];
        float zr[8], zi[8];
        // Z build: Z[k] = E + i*e^{i*pi*k/512}*D, k = 64*k0 + l
        float cw = s_twzb[l].x, sw_ = s_twzb[l].y;
        const float C8 = 0.92387953251128675f, S8 = 0.38268343236508977f; // e^{i*pi/8}
        #pragma unroll
        for (int k0 = 0; k0 < 8; ++k0) {
            int k = (k0<<6) + l;
            float2 xk = Sl[swz(k)];
            float2 xm = Sl[swz(512-k)];
            if (k == 0) { xk.y = 0.f; xm.y = 0.f; }   // zero Im(X0), Im(X512)
            float Er = 0.5f*(xk.x + xm.x), Ei = 0.5f*(xk.y - xm.y);
            float Dr = 0.5f*(xk.x - xm.x), Di = 0.5f*(xk.y + xm.y);
            float Or = cw*Dr - sw_*Di,  Oi = sw_*Dr + cw*Di;
            zr[k0] = Er - Oi;
            zi[k0] = Ei + Or;
            float nc = cw*C8 - sw_*S8; sw_ = sw_*C8 + cw*S8; cw = nc;
        }
        dft8(zr, zi);
        #pragma unroll
        for (int q = 0; q < 8; ++q)
            Sl[swz((q<<6) + l)] = make_float2(zr[q], zi[q]);
        #pragma unroll
        for (int q = 0; q < 8; ++q) {
            float2 t = Sl[swz((a_<<6) + (q<<3) + b_)];
            zr[q] = t.x; zi[q] = t.y;
        }
        { // twiddle2: w64^{n0*k1}, incremental
            float c1 = s_tw64[a_].x, s1 = s_tw64[a_].y;
            float cr = c1, ci = s1;
            #pragma unroll
            for (int q = 1; q < 8; ++q) {
                float tr = zr[q]*cr - zi[q]*ci;
                zi[q] = zr[q]*ci + zi[q]*cr;
                zr[q] = tr;
                float nc = cr*c1 - ci*s1; ci = ci*c1 + cr*s1; cr = nc;
            }
        }
        dft8(zr, zi);
        #pragma unroll
        for (int q = 0; q < 8; ++q)
            Sl[swz((b_<<6) + (q<<3) + a_)] = make_float2(zr[q], zi[q]);
        #pragma unroll
        for (int q = 0; q < 8; ++q) {
            float2 t = Sl[swz((q<<6) + l)];
            zr[q] = t.x; zi[q] = t.y;
        }
        { // twiddle3: w512^{(n1*8+n0)*k2}, incremental
            float c1 = s_tw512[l].x, s1 = s_tw512[l].y;
            float cr = c1, ci = s1;
            #pragma unroll
            for (int q = 1; q < 8; ++q) {
                float tr = zr[q]*cr - zi[q]*ci;
                zi[q] = zr[q]*ci + zi[q]*cr;
                zr[q] = tr;
                float nc = cr*c1 - ci*s1; ci = ci*c1 + cr*s1; cr = nc;
            }
        }
        dft8(zr, zi);
        // output: complex elem n=64q+l holds (x[2n], x[2n+1])
        #pragma unroll
        for (int q = 0; q < 8; ++q)
            Sl[swz((q<<6) + l)] = make_float2(zr[q], zi[q]);
    }
    BAR();   // FFT results visible

    // ---- gather + retire ----
    const int P0 = gg << 11;
    float* yout = out + (size_t)b * 524288;
    float* mout = out + 16ull*524288 + (size_t)b * 524288;

    // interior p in [768,2048): 4 terms, periodic env
    #pragma unroll
    for (int q = 1; q < 4; ++q) {
        int p = (q << 9) + tid;
        if (q > 1 || tid >= 256) {
            int F0 = (p >> 8) - 3;
            float acc = 0.f;
            #pragma unroll
            for (int u = 0; u < 4; ++u) {
                int F = F0 + u;
                int j = p - (F << 8);
                int e = j >> 1;
                acc += ((const float*)&s_slot[F*STRIDE + swz(e)])[j & 1] * s_wt[j];
            }
            float fm = s_ps[(p >> 8) + 4] - s_ps[F0 + 3];
            int s = P0 + p - 384;
            yout[s] = acc * s_envr[p & 255];
            mout[s] = (fm > 0.f) ? 1.0f : 0.0f;
        }
    }
    // left strip p in [0,768)
    #pragma unroll
    for (int v = 0; v < 2; ++v) {
        int p = (v << 9) + tid;
        if (v == 0 || tid < 256) {
            int thi = p >> 8;                 // 0..2
            float acc = 0.f;
            for (int F = 0; F <= thi; ++F) {
                int j = p - (F << 8);
                int e = j >> 1;
                acc += ((const float*)&s_slot[F*STRIDE + swz(e)])[j & 1] * s_wt[j];
            }
            int tlo = (p - 768) >> 8;          // -3..-1
            float fm = s_ps[thi + 4] - s_ps[tlo + 3];
            if (gg == 0) {
                if (p >= 384) {
                    float e = 0.f;
                    for (int t = 0; t <= thi; ++t) {
                        float w = s_wt[p - (t << 8)] * 512.0f;
                        e += w * w;
                    }
                    yout[p - 384] = acc / e;
                    mout[p - 384] = (fm > 0.f) ? 1.0f : 0.0f;
                }
            } else {
                int s = P0 + p - 384;
                if (USE_WS) wsL[(size_t)((b << 8) + gg) * 768 + p] = acc;
                else        atomicAdd(&yout[s], acc);
                mout[s] = (fm > 0.f) ? 1.0f : 0.0f;
            }
        }
    }
    // right strip p in [2048,2816)
    #pragma unroll
    for (int v = 0; v < 2; ++v) {
        int p = 2048 + (v << 9) + tid;
        if (v == 0 || tid < 256) {
            int tlo = (p - 768) >> 8;          // 5..7
            int thm = p >> 8;                  // 8..10 (mask range extends into neighbor)
            float acc = 0.f;
            for (int F = tlo; F < 8; ++F) {
                int j = p - (F << 8);
                int e = j >> 1;
                acc += ((const float*)&s_slot[F*STRIDE + swz(e)])[j & 1] * s_wt[j];
            }
            float fm = s_ps[thm + 4] - s_ps[tlo + 3];
            if (gg == 255) {
                if (p < 2432) {
                    float e = 0.f;
                    for (int t = tlo; t < 8; ++t) {
                        float w = s_wt[p - (t << 8)] * 512.0f;
                        e += w * w;
                    }
                    int s = P0 + p - 384;
                    yout[s] = acc / e;
                    mout[s] = (fm > 0.f) ? 1.0f : 0.0f;
                }
            } else {
                int s = P0 + p - 384;
                if (USE_WS) wsR[(size_t)((b << 8) + gg) * 768 + (p - 2048)] = acc;
                else        atomicAdd(&yout[s], acc);
                mout[s] = (fm > 0.f) ? 1.0f : 0.0f;
            }
        }
    }
}

// ws path: combine the two strip partials, divide by (periodic) env.
__global__ void istft_fixup_ws(const float* __restrict__ wsL, const float* __restrict__ wsR,
                               float* __restrict__ out) {
    int idx = blockIdx.x * 256 + threadIdx.x;
    if (idx >= 16*255*768) return;
    int q  = idx % 768;
    int t_ = idx / 768;
    int g  = (t_ % 255) + 1;
    int b  = t_ / 255;
    float a = wsR[(size_t)((b << 8) + (g-1)) * 768 + q]
            + wsL[(size_t)((b << 8) + g) * 768 + q];
    int j0 = q & 255;
    float e = 0.f;
    #pragma unroll
    for (int u = 0; u < 4; ++u) {
        float w = 0.5f - 0.5f * __cosf(6.2831853071795864f * (float)(j0 + (u<<8)) * (1.0f/1024.0f));
        e += w * w;
    }
    out[(size_t)b*524288 + (size_t)((g << 11) + q - 384)] = a / e;
}

// atomic-fallback path
__global__ void istft_zero(float* __restrict__ out) {
    int idx = blockIdx.x * 256 + threadIdx.x;
    if (idx >= 16*255*768) return;
    int q  = idx % 768;
    int t_ = idx / 768;
    int G  = (t_ % 255) + 1;
    int b  = t_ / 255;
    out[(size_t)b*524288 + (G << 11) + q - 384] = 0.f;
}

__global__ void istft_fixup_at(float* __restrict__ out) {
    int idx = blockIdx.x * 256 + threadIdx.x;
    if (idx >= 16*255*768) return;
    int q  = idx % 768;
    int t_ = idx / 768;
    int G  = (t_ % 255) + 1;
    int b  = t_ / 255;
    int j0 = q & 255;
    float e = 0.f;
    #pragma unroll
    for (int u = 0; u < 4; ++u) {
        float w = 0.5f - 0.5f * __cosf(6.2831853071795864f * (float)(j0 + (u<<8)) * (1.0f/1024.0f));
        e += w * w;
    }
    size_t o = (size_t)b*524288 + (size_t)((G << 11) + q - 384);
    out[o] = out[o] / e;
}

extern "C" void kernel_launch(void* const* d_in, const int* in_sizes, int n_in,
                              void* d_out, int out_size, void* d_ws, size_t ws_size,
                              hipStream_t stream) {
    (void)in_sizes; (void)n_in; (void)out_size;
    const float* spec_re = (const float*)d_in[0];
    const float* spec_im = (const float*)d_in[1];
    const float* mask    = (const float*)d_in[2];
    float* out = (float*)d_out;
    const int nstrip = 16*255*768;
    const size_t ws_need = 2ull * 16 * 256 * 768 * 4;   // 25.2 MB
    if (ws_size >= ws_need && d_ws != nullptr) {
        float* wsL = (float*)d_ws;
        float* wsR = wsL + 16ull*256*768;
        istft_main<true><<<dim3(256, 16), 512, 0, stream>>>(spec_re, spec_im, mask, out, wsL, wsR);
        istft_fixup_ws<<<(nstrip + 255)/256, 256, 0, stream>>>(wsL, wsR, out);
    } else {
        istft_zero<<<(nstrip + 255)/256, 256, 0, stream>>>(out);
        istft_main<false><<<dim3(256, 16), 512, 0, stream>>>(spec_re, spec_im, mask, out, nullptr, nullptr);
        istft_fixup_at<<<(nstrip + 255)/256, 256, 0, stream>>>(out);
    }
}

// Round 7
// 110.938 us; speedup vs baseline: 1.6894x; 1.0140x over previous
//
#include <hip/hip_runtime.h>

#define THREADS 512

// raw barrier: wait LDS ops only (NOT vmcnt) so global loads/stores stay in
// flight across the barrier. "memory" clobber pins C++ LDS access order.
#define BAR() do { asm volatile("s_waitcnt lgkmcnt(0)" ::: "memory"); \
                   __builtin_amdgcn_s_barrier();                      \
                   asm volatile("" ::: "memory"); } while (0)

// -------- radix-8 inverse DFT over register index: u[n] = sum_k v[k] e^{+2*pi*i*n*k/8}
__device__ __forceinline__ void dft8(float* vr, float* vi) {
    float t0r=vr[0]+vr[4], t0i=vi[0]+vi[4];
    float t1r=vr[0]-vr[4], t1i=vi[0]-vi[4];
    float t2r=vr[2]+vr[6], t2i=vi[2]+vi[6];
    float t3r=vr[2]-vr[6], t3i=vi[2]-vi[6];
    float t4r=vr[1]+vr[5], t4i=vi[1]+vi[5];
    float t5r=vr[1]-vr[5], t5i=vi[1]-vi[5];
    float t6r=vr[3]+vr[7], t6i=vi[3]+vi[7];
    float t7r=vr[3]-vr[7], t7i=vi[3]-vi[7];
    float e0r=t0r+t2r, e0i=t0i+t2i;
    float e1r=t1r-t3i, e1i=t1i+t3r;   // t1 + i*t3
    float e2r=t0r-t2r, e2i=t0i-t2i;
    float e3r=t1r+t3i, e3i=t1i-t3r;   // t1 - i*t3
    float o0r=t4r+t6r, o0i=t4i+t6i;
    float o1r=t5r-t7i, o1i=t5i+t7r;
    float o2r=t4r-t6r, o2i=t4i-t6i;
    float o3r=t5r+t7i, o3i=t5i-t7r;
    const float C = 0.70710678118654752f;
    float w1r = C*(o1r - o1i), w1i = C*(o1r + o1i);   // W8^1 * o1
    float w2r = -o2i,          w2i = o2r;             // i * o2
    float w3r = -C*(o3r + o3i), w3i = C*(o3r - o3i);  // W8^3 * o3
    vr[0]=e0r+o0r; vi[0]=e0i+o0i;
    vr[1]=e1r+w1r; vi[1]=e1i+w1i;
    vr[2]=e2r+w2r; vi[2]=e2i+w2i;
    vr[3]=e3r+w3r; vi[3]=e3i+w3i;
    vr[4]=e0r-o0r; vi[4]=e0i-o0i;
    vr[5]=e1r-w1r; vi[5]=e1i-w1i;
    vr[6]=e2r-w2r; vi[6]=e2i-w2i;
    vr[7]=e3r-w3r; vi[7]=e3i-w3i;
}

// one block = (batch b, 8 frames). 512 threads = 8 waves, one FFT per wave.
// load -> tables -> stage(mask-folded, split re/im) -> BAR -> FFT -> BAR -> gather.
template<bool USE_WS>
__global__ __launch_bounds__(512, 6) void istft_main(const float* __restrict__ spec_re,
                                                     const float* __restrict__ spec_im,
                                                     const float* __restrict__ mask,
                                                     float* __restrict__ out,
                                                     float* __restrict__ wsL,
                                                     float* __restrict__ wsR)
{
    const int gg  = blockIdx.x;   // frame-group 0..255 (frames [8g, 8g+8))
    const int b   = blockIdx.y;   // batch 0..15
    const int tid = threadIdx.x;

    __shared__ float  s_slot[8352];   // 8 slots x 522: re [0,4176), im [4176,8352)
    __shared__ float  s_wt[1024];     // hann(j)/512
    __shared__ float  s_envr[256];    // 1 / (periodic fold of hann^2)
    __shared__ float  s_maskx[14];    // mask frames gg*8-3 .. gg*8+10 (OOR = 0)
    __shared__ float  s_ps[15];       // prefix sums of s_maskx
    __shared__ float2 s_twzb[64];     // e^{i*pi*l/512}
    __shared__ float2 s_tw64[8];      // e^{2*pi*i*a/64}
    __shared__ float2 s_tw512[64];    // e^{2*pi*i*l/512}

    // ---- issue global loads FIRST (latency hides under table build) ----
    const size_t base = (size_t)b * 513 * 2048 + (size_t)(gg * 8);
    const int i0 = tid, i1 = tid + 512;
    float4 vr0, vi0, vr1, vi1, vr2, vi2;
    float4 mk;
    float mxv = 0.f;
    {
        size_t off0 = base + (size_t)(i0 >> 1) * 2048 + (size_t)((i0 & 1) * 4);
        vr0 = *(const float4*)(spec_re + off0);
        vi0 = *(const float4*)(spec_im + off0);
        size_t off1 = base + (size_t)(i1 >> 1) * 2048 + (size_t)((i1 & 1) * 4);
        vr1 = *(const float4*)(spec_re + off1);
        vi1 = *(const float4*)(spec_im + off1);
        if (tid < 2) {
            int i2 = 1024 + tid;
            size_t off2 = base + (size_t)(i2 >> 1) * 2048 + (size_t)((i2 & 1) * 4);
            vr2 = *(const float4*)(spec_re + off2);
            vi2 = *(const float4*)(spec_im + off2);
        }
        mk = *(const float4*)(mask + b*2048 + gg*8 + ((tid & 1) << 2));
        if (tid < 14) {
            int gf = gg*8 - 3 + tid;
            mxv = (gf >= 0 && gf < 2048) ? mask[b*2048 + gf] : 0.f;
        }
    }

    // ---- tables (hardware trig; accuracy ~1e-5 << 2e-2 threshold) ----
    for (int i = tid; i < 1024; i += THREADS) {
        float w = 0.5f - 0.5f * __cosf(6.2831853071795864f * (float)i * (1.0f/1024.0f));
        s_wt[i] = w * (1.0f/512.0f);
    }
    if (tid < 256) {
        float e = 0.f;
        #pragma unroll
        for (int k = 0; k < 4; ++k) {
            float w = 0.5f - 0.5f * __cosf(6.2831853071795864f * (float)(tid + (k<<8)) * (1.0f/1024.0f));
            e += w * w;
        }
        s_envr[tid] = 1.0f / e;
    }
    if (tid < 64) {
        float s1, c1, s2, c2;
        __sincosf(3.1415926535897932f * (float)tid * (1.0f/512.0f), &s1, &c1);
        s_twzb[tid] = make_float2(c1, s1);
        __sincosf(6.2831853071795864f * (float)tid * (1.0f/512.0f), &s2, &c2);
        s_tw512[tid] = make_float2(c2, s2);
    }
    if (tid < 8) {
        float s3, c3;
        __sincosf(6.2831853071795864f * (float)tid * (1.0f/64.0f), &s3, &c3);
        s_tw64[tid] = make_float2(c3, s3);
    }
    if (tid < 14) s_maskx[tid] = mxv;

    // ---- stage loaded regs -> LDS, mask folded (frame-major split re/im) ----
    {
        const float* mp = (const float*)&mk;
        int n0 = i0 >> 1, c0 = (i0 & 1) * 4;
        #pragma unroll
        for (int f = 0; f < 4; ++f) {
            s_slot[       (c0+f)*522 + n0] = ((const float*)&vr0)[f] * mp[f];
            s_slot[4176 + (c0+f)*522 + n0] = ((const float*)&vi0)[f] * mp[f];
        }
        int n1 = i1 >> 1, c1 = (i1 & 1) * 4;
        #pragma unroll
        for (int f = 0; f < 4; ++f) {
            s_slot[       (c1+f)*522 + n1] = ((const float*)&vr1)[f] * mp[f];
            s_slot[4176 + (c1+f)*522 + n1] = ((const float*)&vi1)[f] * mp[f];
        }
        if (tid < 2) {
            int c2 = (tid & 1) * 4;    // Nyquist row 512
            #pragma unroll
            for (int f = 0; f < 4; ++f) {
                s_slot[       (c2+f)*522 + 512] = ((const float*)&vr2)[f] * mp[f];
                s_slot[4176 + (c2+f)*522 + 512] = ((const float*)&vi2)[f] * mp[f];
            }
        }
    }
    if (tid == 0) {
        float acc = 0.f;
        s_ps[0] = 0.f;
        #pragma unroll
        for (int i = 0; i < 14; ++i) { acc += s_maskx[i]; s_ps[i+1] = acc; }
    }
    BAR();   // staging + tables visible

    // ---- FFT: wave wv handles frame f=wv, in-place in slot wv ----
    __builtin_amdgcn_s_setprio(1);
    {
        const int wv = tid >> 6, l = tid & 63;
        const int a_ = l >> 3,  b_ = l & 7;
        float* Re = &s_slot[wv*522];
        float* Im = &s_slot[4176 + wv*522];
        float zr[8], zi[8];
        // Z build: Z[k] = E + i*e^{i*pi*k/512}*D, k = 64*k0 + l
        float cw = s_twzb[l].x, sw_ = s_twzb[l].y;
        const float C8 = 0.92387953251128675f, S8 = 0.38268343236508977f; // e^{i*pi/8}
        #pragma unroll
        for (int k0 = 0; k0 < 8; ++k0) {
            int k = (k0<<6) + l;
            float xkr = Re[k],     xki = Im[k];
            float xmr = Re[512-k], xmi = Im[512-k];
            if (k == 0) { xki = 0.f; xmi = 0.f; }   // zero Im(X0), Im(X512)
            float Er = 0.5f*(xkr + xmr), Ei = 0.5f*(xki - xmi);
            float Dr = 0.5f*(xkr - xmr), Di = 0.5f*(xki + xmi);
            float Or = cw*Dr - sw_*Di,  Oi = sw_*Dr + cw*Di;
            zr[k0] = Er - Oi;
            zi[k0] = Ei + Or;
            float nc = cw*C8 - sw_*S8; sw_ = sw_*C8 + cw*S8; cw = nc;
        }
        dft8(zr, zi);
        // exchange 1 (XOR-swizzled, <=2-way)
        #pragma unroll
        for (int q = 0; q < 8; ++q) {
            int idx = (q<<6) + l;
            Re[idx ^ (((idx>>6)&7)<<3)] = zr[q];
            Im[idx ^ (((idx>>6)&7)<<3)] = zi[q];
        }
        #pragma unroll
        for (int q = 0; q < 8; ++q) {
            int idx = (a_<<6) + (q<<3) + b_;
            int ph = idx ^ (((idx>>6)&7)<<3);
            zr[q] = Re[ph]; zi[q] = Im[ph];
        }
        { // twiddle2: w64^{n0*k1}, incremental
            float c1 = s_tw64[a_].x, s1 = s_tw64[a_].y;
            float cr = c1, ci = s1;
            #pragma unroll
            for (int q = 1; q < 8; ++q) {
                float tr = zr[q]*cr - zi[q]*ci;
                zi[q] = zr[q]*ci + zi[q]*cr;
                zr[q] = tr;
                float nc = cr*c1 - ci*s1; ci = ci*c1 + cr*s1; cr = nc;
            }
        }
        dft8(zr, zi);
        // exchange 2
        #pragma unroll
        for (int q = 0; q < 8; ++q) {
            int idx = (b_<<6) + (q<<3) + a_;
            int ph = idx ^ (((idx>>6)&7)<<3);
            Re[ph] = zr[q]; Im[ph] = zi[q];
        }
        #pragma unroll
        for (int q = 0; q < 8; ++q) {
            int idx = (q<<6) + l;
            int ph = idx ^ (((idx>>6)&7)<<3);
            zr[q] = Re[ph]; zi[q] = Im[ph];
        }
        { // twiddle3: w512^{(n1*8+n0)*k2}, incremental
            float c1 = s_tw512[l].x, s1 = s_tw512[l].y;
            float cr = c1, ci = s1;
            #pragma unroll
            for (int q = 1; q < 8; ++q) {
                float tr = zr[q]*cr - zi[q]*ci;
                zi[q] = zr[q]*ci + zi[q]*cr;
                zr[q] = tr;
                float nc = cr*c1 - ci*s1; ci = ci*c1 + cr*s1; cr = nc;
            }
        }
        dft8(zr, zi);
        // output: lane l, reg q holds z[64q + l]; x[2n]=Re z[n], x[2n+1]=Im z[n]
        #pragma unroll
        for (int q = 0; q < 8; ++q) {
            Re[(q<<6) + l] = zr[q];
            Im[(q<<6) + l] = zi[q];
        }
    }
    __builtin_amdgcn_s_setprio(0);
    BAR();   // FFT results visible

    // ---- gather + retire (mask already folded into samples) ----
    const int P0 = gg << 11;
    float* yout = out + (size_t)b * 524288;
    float* mout = out + 16ull*524288 + (size_t)b * 524288;

    // interior p in [768,2048): exactly 4 terms, periodic env, no branches
    #pragma unroll
    for (int q = 1; q < 4; ++q) {
        int p = (q << 9) + tid;
        if (q > 1 || tid >= 256) {
            int F0 = (p >> 8) - 3;
            float acc = 0.f;
            #pragma unroll
            for (int u = 0; u < 4; ++u) {
                int F = F0 + u;
                int j = p - (F << 8);
                acc += s_slot[(j & 1)*4176 + F*522 + (j >> 1)] * s_wt[j];
            }
            float fm = s_ps[(p >> 8) + 4] - s_ps[F0 + 3];
            int s = P0 + p - 384;
            yout[s] = acc * s_envr[p & 255];
            mout[s] = (fm > 0.f) ? 1.0f : 0.0f;
        }
    }
    // left strip p in [0,768)
    #pragma unroll
    for (int v = 0; v < 2; ++v) {
        int p = (v << 9) + tid;
        if (v == 0 || tid < 256) {
            int thi = p >> 8;                 // 0..2
            float acc = 0.f;
            for (int F = 0; F <= thi; ++F) {
                int j = p - (F << 8);
                acc += s_slot[(j & 1)*4176 + F*522 + (j >> 1)] * s_wt[j];
            }
            int tlo = (p - 768) >> 8;          // -3..-1
            float fm = s_ps[thi + 4] - s_ps[tlo + 3];
            if (gg == 0) {
                if (p >= 384) {
                    float e = 0.f;
                    for (int t = 0; t <= thi; ++t) {
                        float w = s_wt[p - (t << 8)] * 512.0f;
                        e += w * w;
                    }
                    yout[p - 384] = acc / e;
                    mout[p - 384] = (fm > 0.f) ? 1.0f : 0.0f;
                }
            } else {
                int s = P0 + p - 384;
                if (USE_WS) wsL[(size_t)((b << 8) + gg) * 768 + p] = acc;
                else        atomicAdd(&yout[s], acc);
                mout[s] = (fm > 0.f) ? 1.0f : 0.0f;
            }
        }
    }
    // right strip p in [2048,2816)
    #pragma unroll
    for (int v = 0; v < 2; ++v) {
        int p = 2048 + (v << 9) + tid;
        if (v == 0 || tid < 256) {
            int tlo = (p - 768) >> 8;          // 5..7
            int thm = p >> 8;                  // 8..10 (mask range spans neighbor)
            float acc = 0.f;
            for (int F = tlo; F < 8; ++F) {
                int j = p - (F << 8);
                acc += s_slot[(j & 1)*4176 + F*522 + (j >> 1)] * s_wt[j];
            }
            float fm = s_ps[thm + 4] - s_ps[tlo + 3];
            if (gg == 255) {
                if (p < 2432) {
                    float e = 0.f;
                    for (int t = tlo; t < 8; ++t) {
                        float w = s_wt[p - (t << 8)] * 512.0f;
                        e += w * w;
                    }
                    int s = P0 + p - 384;
                    yout[s] = acc / e;
                    mout[s] = (fm > 0.f) ? 1.0f : 0.0f;
                }
            } else {
                int s = P0 + p - 384;
                if (USE_WS) wsR[(size_t)((b << 8) + gg) * 768 + (p - 2048)] = acc;
                else        atomicAdd(&yout[s], acc);
                mout[s] = (fm > 0.f) ? 1.0f : 0.0f;
            }
        }
    }
}

// ws path: combine the two strip partials, divide by (periodic) env.
__global__ void istft_fixup_ws(const float* __restrict__ wsL, const float* __restrict__ wsR,
                               float* __restrict__ out) {
    int idx = blockIdx.x * 256 + threadIdx.x;
    if (idx >= 16*255*768) return;
    int q  = idx % 768;
    int t_ = idx / 768;
    int g  = (t_ % 255) + 1;
    int b  = t_ / 255;
    float a = wsR[(size_t)((b << 8) + (g-1)) * 768 + q]
            + wsL[(size_t)((b << 8) + g) * 768 + q];
    int j0 = q & 255;
    float e = 0.f;
    #pragma unroll
    for (int u = 0; u < 4; ++u) {
        float w = 0.5f - 0.5f * __cosf(6.2831853071795864f * (float)(j0 + (u<<8)) * (1.0f/1024.0f));
        e += w * w;
    }
    out[(size_t)b*524288 + (size_t)((g << 11) + q - 384)] = a / e;
}

// atomic-fallback path
__global__ void istft_zero(float* __restrict__ out) {
    int idx = blockIdx.x * 256 + threadIdx.x;
    if (idx >= 16*255*768) return;
    int q  = idx % 768;
    int t_ = idx / 768;
    int G  = (t_ % 255) + 1;
    int b  = t_ / 255;
    out[(size_t)b*524288 + (G << 11) + q - 384] = 0.f;
}

__global__ void istft_fixup_at(float* __restrict__ out) {
    int idx = blockIdx.x * 256 + threadIdx.x;
    if (idx >= 16*255*768) return;
    int q  = idx % 768;
    int t_ = idx / 768;
    int G  = (t_ % 255) + 1;
    int b  = t_ / 255;
    int j0 = q & 255;
    float e = 0.f;
    #pragma unroll
    for (int u = 0; u < 4; ++u) {
        float w = 0.5f - 0.5f * __cosf(6.2831853071795864f * (float)(j0 + (u<<8)) * (1.0f/1024.0f));
        e += w * w;
    }
    size_t o = (size_t)b*524288 + (size_t)((G << 11) + q - 384);
    out[o] = out[o] / e;
}

extern "C" void kernel_launch(void* const* d_in, const int* in_sizes, int n_in,
                              void* d_out, int out_size, void* d_ws, size_t ws_size,
                              hipStream_t stream) {
    (void)in_sizes; (void)n_in; (void)out_size;
    const float* spec_re = (const float*)d_in[0];
    const float* spec_im = (const float*)d_in[1];
    const float* mask    = (const float*)d_in[2];
    float* out = (float*)d_out;
    const int nstrip = 16*255*768;
    const size_t ws_need = 2ull * 16 * 256 * 768 * 4;   // 25.2 MB
    if (ws_size >= ws_need && d_ws != nullptr) {
        float* wsL = (float*)d_ws;
        float* wsR = wsL + 16ull*256*768;
        istft_main<true><<<dim3(256, 16), 512, 0, stream>>>(spec_re, spec_im, mask, out, wsL, wsR);
        istft_fixup_ws<<<(nstrip + 255)/256, 256, 0, stream>>>(wsL, wsR, out);
    } else {
        istft_zero<<<(nstrip + 255)/256, 256, 0, stream>>>(out);
        istft_main<false><<<dim3(256, 16), 512, 0, stream>>>(spec_re, spec_im, mask, out, nullptr, nullptr);
        istft_fixup_at<<<(nstrip + 255)/256, 256, 0, stream>>>(out);
    }
}